// Round 3
// baseline (1144.284 us; speedup 1.0000x reference)
//
#include <hip/hip_runtime.h>

#define TSTEPS 20
#define THRESV 1.0f
#define DECAYV 0.9375f

// ws layout (bytes):
//   [0      .. 32768)   float m1[8192]
//   [32768  .. 65536)   float m2[8192]
//   [65536  .. 65600)   float m3[16]
//   [65600  .. 73280)   u64 s_in_bits[20][48]
//   [73280  .. 93760)   u64 s1_bits[20][128]
//   [93760  .. 114240)  u64 s2_bits[20][128]

__global__ void snn_input_kernel(const float* __restrict__ image,
                                 unsigned long long* __restrict__ s_in_bits) {
    int i = blockIdx.x * 256 + threadIdx.x;   // 0..3071
    float img = image[i];
    float mi = 0.f;
    int word = i >> 6;
    int lane = i & 63;
    for (int t = 0; t < TSTEPS; ++t) {
        mi += img;
        bool fire = (mi >= THRESV);
        if (fire) mi -= THRESV;
        unsigned long long bm = __ballot(fire);
        if (lane == 0) s_in_bits[t * 48 + word] = bm;
    }
}

// wave 0 compacts a firing bitmask into an ascending index list in LDS.
// Deterministic (ascending order, no atomics).
__device__ __forceinline__ int compact_wave0(const unsigned long long* bits, int nwords,
                                             unsigned short* list, int* cntp) {
    int tid = threadIdx.x;
    if (tid < 64) {
        int cnt = 0;
        for (int w = 0; w < nwords; ++w) {
            unsigned long long word = bits ? bits[w] : 0ULL;
            if ((word >> tid) & 1ULL) {
                int pos = cnt + __popcll(word & ((1ULL << tid) - 1ULL));
                list[pos] = (unsigned short)((w << 6) + tid);
            }
            cnt += __popcll(word);
        }
        if (tid == 0) *cntp = cnt;
    }
    __syncthreads();
    return *cntp;
}

// One block handles 32 output columns of a hidden layer (N_out = 8192).
// float4 gather: 8 lanes cover the 32 cols of one row; 32 row-groups,
// group g sums list entries k = g, g+32, ... (4-deep unrolled => 128 rows
// in flight per block). Summation partition & order is IDENTICAL to the
// round-2 kernel (bitwise-equal sums), just 2x more blocks for balance.
template <int NWORDS>
__device__ __forceinline__ void layer_block(const float* __restrict__ W,
                                            const unsigned long long* __restrict__ in_bits,
                                            float* __restrict__ m,
                                            unsigned long long* __restrict__ out_bits,
                                            int blk, char* smem) {
    unsigned short* list = (unsigned short*)smem;            // 16 KiB
    float* partials = (float*)(smem + 16384);                // 4 KiB [32][32]
    int* cntp = (int*)(smem + 16384 + 4096);
    int count = compact_wave0(in_bits, NWORDS, list, cntp);

    int tid = threadIdx.x;
    int c8 = tid & 7;                                        // float4 column 0..7
    int g = tid >> 3;                                        // row-group 0..31
    const float4* Wc = (const float4*)(W + (size_t)blk * 32) + c8;  // row stride 2048 f4

    float ax = 0.f, ay = 0.f, az = 0.f, aw = 0.f;
    int k = g;
    for (; k + 96 < count; k += 128) {                       // 4 x 16B loads in flight
        float4 a0 = Wc[(size_t)list[k]      * 2048];
        float4 a1 = Wc[(size_t)list[k + 32] * 2048];
        float4 a2 = Wc[(size_t)list[k + 64] * 2048];
        float4 a3 = Wc[(size_t)list[k + 96] * 2048];
        ax += a0.x; ay += a0.y; az += a0.z; aw += a0.w;
        ax += a1.x; ay += a1.y; az += a1.z; aw += a1.w;
        ax += a2.x; ay += a2.y; az += a2.z; aw += a2.w;
        ax += a3.x; ay += a3.y; az += a3.z; aw += a3.w;
    }
    for (; k < count; k += 32) {
        float4 a = Wc[(size_t)list[k] * 2048];
        ax += a.x; ay += a.y; az += a.z; aw += a.w;
    }
    ((float4*)partials)[g * 8 + c8] = make_float4(ax, ay, az, aw);
    __syncthreads();

    if (tid < 32) {  // lanes 0..31 of wave 0: one lane per column, fixed order
        float s = 0.f;
        #pragma unroll
        for (int gg = 0; gg < 32; ++gg) s += partials[gg * 32 + tid];
        int j = blk * 32 + tid;
        float v = m[j] + s;
        bool fire = (v >= THRESV);
        if (fire) v -= THRESV;
        m[j] = fire ? v : v * DECAYV;
        unsigned long long bm = __ballot(fire);   // lanes 32..63 inactive -> 0
        if (tid == 0) ((unsigned*)out_bits)[blk] = (unsigned)bm;
    }
}

// Layer 3: 10 outputs, W3 is 8192x10 (tiny). 32 groups x 16 cols.
__device__ __forceinline__ void layer3_block(const float* __restrict__ W3,
                                             const unsigned long long* __restrict__ s2p,
                                             float* __restrict__ m3,
                                             float* __restrict__ out_row, char* smem) {
    unsigned short* list = (unsigned short*)smem;
    float* partials = (float*)(smem + 16384);                // 32*16 floats
    int* cntp = (int*)(smem + 16384 + 4096);
    int count = compact_wave0(s2p, 128, list, cntp);

    int tid = threadIdx.x;
    int col = tid & 15;
    int g = tid >> 4;                                        // 0..15 (256 thr)
    float acc = 0.f;
    if (col < 10) {
        for (int k = g; k < count; k += 32)
            acc += W3[(size_t)list[k] * 10 + col];
        for (int k = g + 16; k < count; k += 32)
            acc += W3[(size_t)list[k] * 10 + col];
    }
    // NOTE: to keep the exact round-2 summation order for layer 3 we emulate
    // 32 groups with 16 physical groups doing two strided passes, then store
    // both partial sets.
    partials[g * 16 + col] = acc;  // placeholder (overwritten below)
    __syncthreads();
    // Recompute with true 32-group partition for bitwise identity:
    {
        float a0 = 0.f, a1 = 0.f;
        if (col < 10) {
            for (int k = g; k < count; k += 32)      a0 += W3[(size_t)list[k] * 10 + col];
            for (int k = g + 16; k < count; k += 32) a1 += W3[(size_t)list[k] * 10 + col];
        }
        partials[g * 16 + col] = a0;
        partials[(g + 16) * 16 + col] = a1;
    }
    __syncthreads();

    if (tid < 10) {
        float s = 0.f;
        for (int gg = 0; gg < 32; ++gg) s += partials[gg * 16 + tid];
        float v = m3[tid] + s;
        bool fire = (v >= THRESV);
        if (fire) v -= THRESV;
        m3[tid] = fire ? v : v * DECAYV;
        out_row[tid] = fire ? 1.f : 0.f;
    }
}

__global__ void __launch_bounds__(256)
snn_step_kernel(const float* __restrict__ W1, const float* __restrict__ W2,
                const float* __restrict__ W3,
                float* __restrict__ m1, float* __restrict__ m2, float* __restrict__ m3,
                const unsigned long long* __restrict__ sin_b,   // this step's input spikes
                const unsigned long long* __restrict__ s1p_b,   // prev-step layer1 spikes (or null)
                const unsigned long long* __restrict__ s2p_b,   // prev-step layer2 spikes (or null)
                unsigned long long* __restrict__ s1_out,
                unsigned long long* __restrict__ s2_out,
                float* __restrict__ out_row) {
    __shared__ __align__(16) char smem[16384 + 4096 + 16];
    int b = blockIdx.x;
    if (b < 256) {
        layer_block<48>(W1, sin_b, m1, s1_out, b, smem);
    } else if (b < 512) {
        layer_block<128>(W2, s1p_b, m2, s2_out, b - 256, smem);
    } else {
        layer3_block(W3, s2p_b, m3, out_row, smem);
    }
}

extern "C" void kernel_launch(void* const* d_in, const int* in_sizes, int n_in,
                              void* d_out, int out_size, void* d_ws, size_t ws_size,
                              hipStream_t stream) {
    const float* image = (const float*)d_in[0];
    const float* W1 = (const float*)d_in[1];
    const float* W2 = (const float*)d_in[2];
    const float* W3 = (const float*)d_in[3];
    float* out = (float*)d_out;

    char* ws = (char*)d_ws;
    float* m1 = (float*)ws;
    float* m2 = m1 + 8192;
    float* m3 = m2 + 8192;  // 16 floats
    unsigned long long* s_in_bits = (unsigned long long*)(ws + 65600);   // [20][48]
    unsigned long long* s1_bits = s_in_bits + TSTEPS * 48;               // [20][128]
    unsigned long long* s2_bits = s1_bits + TSTEPS * 128;                // [20][128]

    // zero membranes + output (harness poisons both; state must reset every launch)
    hipMemsetAsync(d_ws, 0, 65600, stream);
    hipMemsetAsync(d_out, 0, (size_t)out_size * sizeof(float), stream);

    snn_input_kernel<<<12, 256, 0, stream>>>(image, s_in_bits);

    for (int t = 0; t < TSTEPS; ++t) {
        snn_step_kernel<<<513, 256, 0, stream>>>(
            W1, W2, W3, m1, m2, m3,
            s_in_bits + t * 48,
            t ? s1_bits + (t - 1) * 128 : nullptr,
            t ? s2_bits + (t - 1) * 128 : nullptr,
            s1_bits + t * 128,
            s2_bits + t * 128,
            out + (t + 1) * 10);
    }
}

// Round 4
// 715.110 us; speedup vs baseline: 1.6002x; 1.6002x over previous
//
#include <hip/hip_runtime.h>

#define TSTEPS 20
#define THRESV 1.0f
#define DECAYV 0.9375f

// ws byte layout:
//   [0,      7680)   u64 s_in_bits[20][48]
//   [7680,  28160)   u64 s1_bits[20][128]
//   [28160, 48640)   u64 s2_bits[20][128]
//   [48640, 48720)   u32 cnt1[20]   (memset to 0 each launch)
//   [48720, 48800)   u32 cnt2[20]   (memset to 0 each launch)

__global__ void snn_input_kernel(const float* __restrict__ image,
                                 unsigned long long* __restrict__ s_in_bits) {
    int i = blockIdx.x * 256 + threadIdx.x;   // 0..3071
    float img = image[i];
    float mi = 0.f;
    int word = i >> 6, lane = i & 63;
    for (int t = 0; t < TSTEPS; ++t) {
        mi += img;
        bool fire = (mi >= THRESV);
        if (fire) mi -= THRESV;
        unsigned long long bm = __ballot(fire);
        if (lane == 0) s_in_bits[t * 48 + word] = bm;
    }
}

struct SMem {
    unsigned short list[8192];      // 16 KiB compacted firing-row indices
    float partials[2048];           // 8 KiB  [32 groups][64 cols]
    unsigned long long bw[128];     // snapshot of the bitmask words
    unsigned pc[128];               // per-word popcounts
    int cntp;
    float mcol[64];                 // this block's membrane slice (persistent)
};

__device__ __forceinline__ void wait_cnt(const unsigned* p, unsigned target) {
    if (threadIdx.x == 0) {
        while (__hip_atomic_load(p, __ATOMIC_ACQUIRE, __HIP_MEMORY_SCOPE_AGENT) < target)
            __builtin_amdgcn_s_sleep(16);
    }
    __syncthreads();
}

// Deterministic parallel compaction: 8 waves each own NW/8 words; ascending
// list order identical to the serial version => bitwise-identical sums.
template <int NW>
__device__ __forceinline__ int compact_par(const unsigned long long* bits, SMem& sm) {
    int tid = threadIdx.x;
    if (tid < NW) {
        unsigned long long w = __hip_atomic_load(&bits[tid], __ATOMIC_RELAXED, __HIP_MEMORY_SCOPE_AGENT);
        sm.bw[tid] = w;
        sm.pc[tid] = (unsigned)__popcll(w);
    }
    __syncthreads();
    constexpr int WPW = NW / 8;
    int wave = tid >> 6, lane = tid & 63;
    int w0 = wave * WPW;
    int base = 0;
    for (int i = lane; i < w0; i += 64) base += (int)sm.pc[i];
    #pragma unroll
    for (int off = 1; off < 64; off <<= 1) base += __shfl_xor(base, off);
    if (wave == 0) {
        int tot = 0;
        for (int i = lane; i < NW; i += 64) tot += (int)sm.pc[i];
        #pragma unroll
        for (int off = 1; off < 64; off <<= 1) tot += __shfl_xor(tot, off);
        if (lane == 0) sm.cntp = tot;
    }
    for (int i = 0; i < WPW; ++i) {
        unsigned long long w = sm.bw[w0 + i];
        if ((w >> lane) & 1ull) {
            int pos = base + __popcll(w & ((1ull << lane) - 1ull));
            sm.list[pos] = (unsigned short)(((w0 + i) << 6) + lane);
        }
        base += __popcll(w);
    }
    __syncthreads();
    return sm.cntp;
}

// 64-column gather + LIF epilogue; summation partition identical to round 2
// (c=tid&15 float4 cols, g=tid>>4 row-groups, 4-deep stride-32 unroll).
__device__ __forceinline__ void gather_lif64(const float* __restrict__ W, int colbase,
                                             int count, SMem& sm,
                                             unsigned long long* dst_word,
                                             unsigned* cnt_pub) {
    int tid = threadIdx.x;
    const float4* Wc = (const float4*)(W + (size_t)colbase) + (tid & 15);
    float ax = 0.f, ay = 0.f, az = 0.f, aw = 0.f;
    int k = tid >> 4;
    for (; k + 96 < count; k += 128) {
        float4 a0 = Wc[(size_t)sm.list[k]      * 2048];
        float4 a1 = Wc[(size_t)sm.list[k + 32] * 2048];
        float4 a2 = Wc[(size_t)sm.list[k + 64] * 2048];
        float4 a3 = Wc[(size_t)sm.list[k + 96] * 2048];
        ax += a0.x; ay += a0.y; az += a0.z; aw += a0.w;
        ax += a1.x; ay += a1.y; az += a1.z; aw += a1.w;
        ax += a2.x; ay += a2.y; az += a2.z; aw += a2.w;
        ax += a3.x; ay += a3.y; az += a3.z; aw += a3.w;
    }
    for (; k < count; k += 32) {
        float4 a = Wc[(size_t)sm.list[k] * 2048];
        ax += a.x; ay += a.y; az += a.z; aw += a.w;
    }
    ((float4*)sm.partials)[(tid >> 4) * 16 + (tid & 15)] = make_float4(ax, ay, az, aw);
    __syncthreads();

    if (tid < 64) {
        float s = 0.f;
        #pragma unroll
        for (int gg = 0; gg < 32; ++gg) s += sm.partials[gg * 64 + tid];
        float v = sm.mcol[tid] + s;
        bool fire = (v >= THRESV);
        if (fire) v -= THRESV;
        sm.mcol[tid] = fire ? v : v * DECAYV;
        unsigned long long bm = __ballot(fire);
        if (tid == 0) {
            __hip_atomic_store(dst_word, bm, __ATOMIC_RELEASE, __HIP_MEMORY_SCOPE_AGENT);
            __hip_atomic_fetch_add(cnt_pub, 1u, __ATOMIC_RELEASE, __HIP_MEMORY_SCOPE_AGENT);
        }
    }
}

__global__ void __launch_bounds__(512)
snn_persistent(const float* __restrict__ W1, const float* __restrict__ W2,
               const float* __restrict__ W3,
               const unsigned long long* __restrict__ s_in_bits,
               unsigned long long* __restrict__ s1_bits,
               unsigned long long* __restrict__ s2_bits,
               unsigned* __restrict__ cnt1, unsigned* __restrict__ cnt2,
               float* __restrict__ out) {
    __shared__ __align__(16) SMem sm;
    int tid = threadIdx.x;
    int b = blockIdx.x;
    if (tid < 64) sm.mcol[tid] = 0.f;   // wave 0 writes, wave 0 reads later

    if (b < 128) {
        // ---- layer-1 role: depends only on precomputed input spikes ----
        for (int t = 0; t < TSTEPS; ++t) {
            int count = compact_par<48>(s_in_bits + (size_t)t * 48, sm);
            gather_lif64(W1, b * 64, count, sm, &s1_bits[t * 128 + b], &cnt1[t]);
        }
    } else if (b < 256) {
        // ---- layer-2 role: consumes s1[t-1] ----
        int cb = b - 128;
        if (tid == 0) {   // step 0: zero input -> no fire, membrane stays 0
            __hip_atomic_store(&s2_bits[cb], 0ull, __ATOMIC_RELEASE, __HIP_MEMORY_SCOPE_AGENT);
            __hip_atomic_fetch_add(&cnt2[0], 1u, __ATOMIC_RELEASE, __HIP_MEMORY_SCOPE_AGENT);
        }
        for (int t = 1; t < TSTEPS; ++t) {
            wait_cnt(&cnt1[t - 1], 128);
            int count = compact_par<128>(s1_bits + (size_t)(t - 1) * 128, sm);
            gather_lif64(W2, cb * 64, count, sm, &s2_bits[t * 128 + cb], &cnt2[t]);
        }
    } else {
        // ---- layer-3 role (single block): consumes s2[t-1] ----
        if (tid < 10) { out[tid] = 0.f; out[10 + tid] = 0.f; }  // rows 0,1
        for (int t = 1; t < TSTEPS; ++t) {
            wait_cnt(&cnt2[t - 1], 128);
            int count = compact_par<128>(s2_bits + (size_t)(t - 1) * 128, sm);
            int col = tid & 15, g = tid >> 4;                    // 32 groups
            float acc = 0.f;
            if (col < 10) {
                for (int k = g; k < count; k += 32)
                    acc += W3[(size_t)sm.list[k] * 10 + col];
            }
            sm.partials[g * 16 + col] = acc;
            __syncthreads();
            if (tid < 10) {
                float s = 0.f;
                for (int gg = 0; gg < 32; ++gg) s += sm.partials[gg * 16 + tid];
                float v = sm.mcol[tid] + s;
                bool fire = (v >= THRESV);
                if (fire) v -= THRESV;
                sm.mcol[tid] = fire ? v : v * DECAYV;
                out[(t + 1) * 10 + tid] = fire ? 1.f : 0.f;
            }
            __syncthreads();
        }
    }
}

extern "C" void kernel_launch(void* const* d_in, const int* in_sizes, int n_in,
                              void* d_out, int out_size, void* d_ws, size_t ws_size,
                              hipStream_t stream) {
    const float* image = (const float*)d_in[0];
    const float* W1 = (const float*)d_in[1];
    const float* W2 = (const float*)d_in[2];
    const float* W3 = (const float*)d_in[3];
    float* out = (float*)d_out;

    char* ws = (char*)d_ws;
    unsigned long long* s_in_bits = (unsigned long long*)ws;            // [20][48]
    unsigned long long* s1_bits = (unsigned long long*)(ws + 7680);     // [20][128]
    unsigned long long* s2_bits = (unsigned long long*)(ws + 28160);    // [20][128]
    unsigned* cnt1 = (unsigned*)(ws + 48640);                           // [20]
    unsigned* cnt2 = (unsigned*)(ws + 48720);                           // [20]

    // counters must be zero before the persistent kernel starts (each replay)
    hipMemsetAsync(ws + 48640, 0, 160, stream);

    snn_input_kernel<<<12, 256, 0, stream>>>(image, s_in_bits);

    snn_persistent<<<257, 512, 0, stream>>>(W1, W2, W3, s_in_bits,
                                            s1_bits, s2_bits, cnt1, cnt2, out);
}